// Round 8
// baseline (36.977 us; speedup 1.0000x reference)
//
#include <hip/hip_runtime.h>

#define HH 256
#define WW 256
#define NB 4
#define NC 4
#define NPIX (HH*WW)            // 65536
#define NIMG (NB*NC)            // 16
#define TOTAL (NB*NC*HH*WW)     // 1048576
#define INF_G (1<<30)

__device__ __forceinline__ float wave_reduce(float v) {
    #pragma unroll
    for (int off = 32; off > 0; off >>= 1) v += __shfl_down(v, off);
    return v;
}

// distance from x to nearest set bit in a 256-bit mask (4 u64 words); INT_MAX if none
__device__ __forceinline__ int nearest_dist(const unsigned long long* m, int x) {
    int best = 0x7fffffff;
    #pragma unroll
    for (int w = 0; w < 4; ++w) {
        unsigned long long mm = m[w];
        if (!mm) continue;
        int rel = x - (w << 6);
        // left side: highest set bit at position <= rel
        unsigned long long lmask = (rel >= 63) ? ~0ull
                                 : ((rel < 0) ? 0ull : ((2ull << (rel & 63)) - 1ull));
        unsigned long long lm = mm & lmask;
        if (lm) best = min(best, rel - (63 - __clzll(lm)));
        // right side: lowest set bit at position >= rel
        unsigned long long rmask = (rel <= 0) ? ~0ull
                                 : ((rel > 63) ? 0ull : (~0ull << (rel & 63)));
        unsigned long long rm = mm & rmask;
        if (rm) best = min(best, (__ffsll((long long)rm) - 1) - rel);
    }
    return best;
}

// Kernel 1: softmax + row ballot masks + transposed (p-t)^2. block=(b,y), thread=x.
//   masks[((img*HH + y)*2 + src)*4 + w]  (src 0 = fgP sites, 1 = fgT sites)
//   peT[(img*WW + x)*HH + y] = (p - t)^2
// Also zeroes out[0] (timed replays don't re-poison; kernel boundary publishes it).
__global__ void build_masks(const float* __restrict__ pred, const int* __restrict__ target,
                            unsigned long long* __restrict__ masks, float* __restrict__ peT,
                            float* __restrict__ out) {
    int blk = blockIdx.x;           // b*256 + y
    int b = blk >> 8, y = blk & 255;
    int x = threadIdx.x;

    if (blk == 0 && x == 0) out[0] = 0.0f;

    const float* base = pred + (((size_t)b * NC) * HH + y) * WW + x;
    float v0 = base[0 * (size_t)NPIX];
    float v1 = base[1 * (size_t)NPIX];
    float v2 = base[2 * (size_t)NPIX];
    float v3 = base[3 * (size_t)NPIX];
    float m = fmaxf(fmaxf(v0, v1), fmaxf(v2, v3));
    float e0 = expf(v0 - m), e1 = expf(v1 - m), e2 = expf(v2 - m), e3 = expf(v3 - m);
    float inv = 1.0f / (e0 + e1 + e2 + e3);
    float p[4] = { e0 * inv, e1 * inv, e2 * inv, e3 * inv };

    int tc = target[((size_t)b * HH + y) * WW + x];

    __shared__ unsigned long long sm[NC][2][4];   // [class][src][word]
    int lane = x & 63, wv = x >> 6;
    #pragma unroll
    for (int c = 0; c < 4; ++c) {
        unsigned long long bp = __ballot(p[c] > 0.5f);
        unsigned long long bt = __ballot(tc == c);
        if (lane == 0) { sm[c][0][wv] = bp; sm[c][1][wv] = bt; }
        float t = (tc == c) ? 1.0f : 0.0f;
        float d = p[c] - t;
        peT[(((size_t)(b * NC + c)) * WW + x) * HH + y] = d * d;   // transposed
    }
    __syncthreads();

    if (x < 32) {
        int c = x >> 3, s = (x >> 2) & 1, w = x & 3;
        masks[(((size_t)(b * NC + c) * HH + y) * 2 + s) * 4 + w] = sm[c][s][w];
    }
}

// Kernel 2: column DT + loss + final accumulation.
// block = (img, 4-column chunk), 1024 threads = (k = col-in-chunk, y).
// Loads the image's row masks (16 KB) to LDS, recomputes each pixel's row-distance
// against the OPPOSITE set of its own class (same-set distance is exactly 0),
// builds the 4 g variants in LDS, outward column search with early exit.
// Block partial goes to out[0] via one hw fp32 atomic per block.
__global__ __launch_bounds__(1024) void cols_loss(const unsigned long long* __restrict__ masks,
                                                  const float* __restrict__ peT,
                                                  float* __restrict__ out) {
    int bid = blockIdx.x;
    int img = bid >> 6;
    int xbase = (bid & 63) << 2;
    int tid = threadIdx.x;
    int k = tid >> 8, y = tid & 255;
    int x = xbase + k;
    int lane = tid & 63, wv = tid >> 6;

    __shared__ unsigned long long sm[HH * 8];   // [y][src][w]: 16 KB
    __shared__ int g[4][4][HH];                 // [k][variant][y]: 16 KB
    __shared__ int sF[2][16];
    __shared__ float sred[16];

    const unsigned long long* mbase = masks + (size_t)img * HH * 8;
    sm[tid]        = mbase[tid];
    sm[tid + 1024] = mbase[tid + 1024];
    __syncthreads();

    unsigned long long mp[4], mt[4];
    #pragma unroll
    for (int w = 0; w < 4; ++w) { mp[w] = sm[y * 8 + w]; mt[w] = sm[y * 8 + 4 + w]; }

    int fgP = (int)((mp[x >> 6] >> (x & 63)) & 1);
    int fgT = (int)((mt[x >> 6] >> (x & 63)) & 1);

    unsigned long long sel[4];
    unsigned long long flipP = fgP ? ~0ull : 0ull;   // fg -> search complement set
    #pragma unroll
    for (int w = 0; w < 4; ++w) sel[w] = mp[w] ^ flipP;
    int dP = nearest_dist(sel, x);
    int vP = (dP > 255) ? INF_G : dP * dP;

    unsigned long long flipT = fgT ? ~0ull : 0ull;
    #pragma unroll
    for (int w = 0; w < 4; ++w) sel[w] = mt[w] ^ flipT;
    int dT = nearest_dist(sel, x);
    int vT = (dT > 255) ? INF_G : dT * dT;

    g[k][0][y] = fgP ? vP : 0;     // dist^2(row y, sites=~fgP)  (fg_dist input)
    g[k][1][y] = fgP ? 0 : vP;     // dist^2(row y, sites= fgP)  (bg_dist input)
    g[k][2][y] = fgT ? vT : 0;
    g[k][3][y] = fgT ? 0 : vT;

    // image-wide any(fg) flags (row-property, redundantly computed across k-groups)
    unsigned long long bP = __ballot((mp[0] | mp[1] | mp[2] | mp[3]) != 0ull);
    unsigned long long bT = __ballot((mt[0] | mt[1] | mt[2] | mt[3]) != 0ull);
    if (lane == 0) { sF[0][wv] = (bP != 0ull); sF[1][wv] = (bT != 0ull); }
    __syncthreads();

    int hs1 = 0, hs3 = 0;
    #pragma unroll
    for (int i = 0; i < 16; ++i) { hs1 |= sF[0][i]; hs3 |= sF[1][i]; }

    const int* gP = fgP ? g[k][0] : g[k][1];
    const int* gT = fgT ? g[k][2] : g[k][3];

    float dtP, dtT;
    {
        int best = gP[y];
        for (int s = 1; s < HH; ++s) {
            int ss = s * s;
            if (ss >= best) break;
            int jm = y - s;
            if (jm >= 0) best = min(best, gP[jm] + ss);
            int jp = y + s;
            if (jp < HH) best = min(best, gP[jp] + ss);
        }
        dtP = (best >= INF_G) ? sqrtf(1.0e9f) : sqrtf((float)best);
    }
    {
        int best = gT[y];
        for (int s = 1; s < HH; ++s) {
            int ss = s * s;
            if (ss >= best) break;
            int jm = y - s;
            if (jm >= 0) best = min(best, gT[jm] + ss);
            int jp = y + s;
            if (jp < HH) best = min(best, gT[jp] + ss);
        }
        dtT = (best >= INF_G) ? sqrtf(1.0e9f) : sqrtf((float)best);
    }

    float pe = peT[((size_t)img * WW + x) * HH + y];
    float pd = hs1 ? dtP : 0.0f;    // other pair member is exactly 0
    float td = hs3 ? dtT : 0.0f;
    float val = pe * (pd * pd + td * td);

    val = wave_reduce(val);
    if (lane == 0) sred[wv] = val;
    __syncthreads();
    if (tid == 0) {
        float blocksum = 0.0f;
        #pragma unroll
        for (int i = 0; i < 16; ++i) blocksum += sred[i];
        unsafeAtomicAdd(out, blocksum * (1.0f / (float)TOTAL));
    }
}

extern "C" void kernel_launch(void* const* d_in, const int* in_sizes, int n_in,
                              void* d_out, int out_size, void* d_ws, size_t ws_size,
                              hipStream_t stream) {
    const float* pred  = (const float*)d_in[0];
    const int* target  = (const int*)d_in[1];
    float* out = (float*)d_out;

    float* ws = (float*)d_ws;
    unsigned long long* masks = (unsigned long long*)ws;        // 16*256*8 u64 = 256 KB
    float* peT = ws + 65536;                                    // 1,048,576 floats (4 MB)

    build_masks<<<NB * HH, 256, 0, stream>>>(pred, target, masks, peT, out);
    cols_loss<<<NIMG * 64, 1024, 0, stream>>>(masks, peT, out);
}